// Round 2
// baseline (429.736 us; speedup 1.0000x reference)
//
#include <hip/hip_runtime.h>

// TV-L1 optical flow, B=4, 512x512, 20 iters — temporal blocking (ghost zones)
// R7: R6 + pinned register budget. R6's counters showed VGPR_Count=64 with
// ~185 MB excess FETCH / ~73 MB excess WRITE per dispatch = scratch spills:
// the allocator targeted 64 VGPRs (8 waves/SIMD) even though LDS=153.6KB caps
// the CU at 1 workgroup = 4 waves/SIMD. amdgpu_waves_per_eu(4,4) pins the
// budget at 512/4 = 128 VGPRs, matching the LDS-imposed occupancy.
// Also: inb[] packed into a single bitmask VGPR.
// Carried from R6:
//   - gl recomputed as (li<<9)+lj+cb (no gofs array).
//   - p-state center values read from LDS in main loop (no rpa/rpb mirrors).
//   - soft-threshold select as d = clamp(rho*rnv, -tl, tl) (v_med3), exact
//     vs reference (|rho|<th <=> |rho*rnv|<tl, continuous at boundary).
//   LDS: su=(u1,u2), spa=(p11,p21), spb=(p12,p22), 3 x 6400 x 8B = 153.6 KB.
// Halo L=6/R=10 (80x80 region per 64x64 tile). Zero-padding reproduced by
// forcing u=p=0 on out-of-image pixels. Last kernel skips the dead 20th
// p-update and fuses the 3x3 avgpool.

#define HH 512
#define WW 512
#define BB 4
constexpr int HW   = HH * WW;
constexpr int NTOT = BB * HW;
constexpr float EPS = 1e-8f;

#define T 64          // output tile edge
#define HALO_L 6      // left/top halo
#define REG 80        // region edge = 64 + 6 + 10
#define NPX (REG * REG)   // 6400
#define TPB 1024
#define SLOTS 7       // ceil(6400/1024)
#define NBLK 256      // 4 images x 8x8 tiles
#define XR 82         // x1 staging edge (region + 1-ring for 3x3 gradient)
#define XN (XR * XR)  // 6724 <= 12800 floats available in spa

// phase: 0 = first (u,p zero-init, write back), 1 = middle (load, write
// back), 2 = last (load, 5 u-phases + 4 p-phases, fused avgpool -> out).
__global__ __launch_bounds__(TPB, 1)
__attribute__((amdgpu_waves_per_eu(4, 4)))
void k_fused(
    const float* __restrict__ x,
    float2* __restrict__ ug, float4* __restrict__ pg,
    const float* __restrict__ lam_p, const float* __restrict__ tau_p,
    const float* __restrict__ theta_p,
    const float* __restrict__ wxp, const float* __restrict__ wyp,
    float* __restrict__ out, int phase)
{
    __shared__ float2 su[NPX];    // (u1,u2)
    __shared__ float2 spa[NPX];   // (p11,p21); doubles as x1 staging buffer
    __shared__ float2 spb[NPX];   // (p12,p22)   -> 153.6 KB total

    const int tid  = threadIdx.x;
    const int blk  = blockIdx.x;
    const int bimg = blk >> 6;
    const int t    = blk & 63;
    const int gi0  = (t >> 3) * T;
    const int gj0  = (t & 7) * T;

    const float lam = lam_p[0], theta = theta_p[0];
    const float r   = tau_p[0] / theta;
    const float tl  = theta * lam;
    const float wx0 = wxp[0], wx1 = wxp[1], wx2 = wxp[2];
    const float wy0 = wyp[0], wy1 = wyp[1], wy2 = wyp[2];

    const int gbase = bimg * HW;
    const int cb    = (gi0 - HALO_L) * WW + (gj0 - HALO_L);  // gl=(li<<9)+lj+cb
    const float* x0p = x + (size_t)bimg * 2 * HW;
    const float* x1p = x0p + HW;

    int  lis[SLOTS], ljs[SLOTS];
    unsigned inbm = 0u;           // bit s: slot s own-pixel is in-image
    float2 ruv[SLOTS];            // own-pixel u mirror (hot in both phases)
    float2 tpa[SLOTS], tpb[SLOTS];  // pass1->pass3 p-state temps ONLY
    float  x0v[SLOTS];            // pass1->pass2 temp ONLY

    // ---- pass 1: stage x1 into spa-as-float; precompute per-slot indices;
    //      issue state loads early (consumed in pass 3, overlap statics) ----
    #pragma unroll
    for (int s = 0; s < SLOTS; ++s) {
        int idx = tid + s * TPB;
        if (idx < XN) {
            int li = idx / XR, lj = idx - li * XR;
            int gi = gi0 + li - (HALO_L + 1), gj = gj0 + lj - (HALO_L + 1);
            bool in = ((unsigned)gi < HH) & ((unsigned)gj < WW);
            ((float*)spa)[idx] = in ? x1p[gi * WW + gj] : 0.f;
        }
        if (idx < NPX) {
            int li = idx / REG, lj = idx - li * REG;
            lis[s] = li; ljs[s] = lj;
            int gi = gi0 + li - HALO_L, gj = gj0 + lj - HALO_L;
            bool in = ((unsigned)gi < HH) & ((unsigned)gj < WW);
            inbm |= (in ? (1u << s) : 0u);
            int gl = (li << 9) + lj + cb;     // == gi*WW+gj, valid only when in
            float2 uv = make_float2(0.f, 0.f);
            float4 p4 = make_float4(0.f, 0.f, 0.f, 0.f);
            float xv = 0.f;
            if (in) {
                xv = x0p[gl];
                if (phase != 0) {
                    uv = ug[gbase + gl];
                    p4 = pg[gbase + gl];
                }
            }
            x0v[s] = xv;
            ruv[s] = uv;
            tpa[s] = make_float2(p4.x, p4.y);
            tpb[s] = make_float2(p4.z, p4.w);
        }
    }
    __syncthreads();

    // ---- pass 2: statics (gx,gy,rc,1/nm) from staged x1 -------------------
    float rgx[SLOTS], rgy[SLOTS], rrc[SLOTS], rnv[SLOTS];
    const float* stg = (const float*)spa;
    #pragma unroll
    for (int s = 0; s < SLOTS; ++s) {
        int idx = tid + s * TPB;
        if (idx < NPX) {
            int sc = (lis[s] + 1) * XR + (ljs[s] + 1);
            float a00 = stg[sc - XR - 1], a01 = stg[sc - XR], a02 = stg[sc - XR + 1];
            float a10 = stg[sc - 1],      a11 = stg[sc],      a12 = stg[sc + 1];
            float a20 = stg[sc + XR - 1], a21 = stg[sc + XR], a22 = stg[sc + XR + 1];
            const float c6 = 1.f / 6.f;
            float gxv = c6 * (-a00 + a02 - 2.f * a10 + 2.f * a12 - a20 + a22);
            float gyv = c6 * (-a00 - 2.f * a01 - a02 + a20 + 2.f * a21 + a22);
            float nm  = gxv * gxv + gyv * gyv + EPS;
            rgx[s] = gxv; rgy[s] = gyv;
            rrc[s] = a11 - x0v[s];           // zero-padded conv semantics held
            rnv[s] = __builtin_amdgcn_rcpf(nm);
        }
    }
    __syncthreads();

    // ---- pass 3: fill LDS state (overwrites staging) ----------------------
    #pragma unroll
    for (int s = 0; s < SLOTS; ++s) {
        int idx = tid + s * TPB;
        if (idx < NPX) {
            su[idx]  = ruv[s];
            spa[idx] = tpa[s];
            spb[idx] = tpb[s];
        }
    }
    __syncthreads();

    // ---- 5 fused iterations ----------------------------------------------
    for (int k = 1; k <= 5; ++k) {
        // u-phase over li,lj in [k, REG-2k]  (valid cone of u^k)
        const int lo = k, hi_u = REG - 2 * k;
        #pragma unroll
        for (int s = 0; s < SLOTS; ++s) {
            int idx = tid + s * TPB;
            if (idx >= NPX) continue;
            int li = lis[s], lj = ljs[s];
            if (li < lo || li > hi_u || lj < lo || lj > hi_u) continue;
            float2 uv = ruv[s];
            float rho = rrc[s] + rgx[s] * uv.x + rgy[s] * uv.y;
            // |rho| < th  <=>  |rho*rnv| < tl  (nm>0); boundary continuous,
            // so d = clamp(rho*rnv, -tl, tl) == reference select (v_med3).
            float tt = rho * rnv[s];
            float d  = fminf(fmaxf(tt, -tl), tl);
            float v1 = uv.x - d * rgx[s];
            float v2 = uv.y - d * rgy[s];
            float2 pal = spa[idx - 1],   pac = spa[idx],   par = spa[idx + 1];
            float2 pbt = spb[idx - REG], pbc = spb[idx],   pbb = spb[idx + REG];
            float div1 = wx0 * pal.x + wx1 * pac.x + wx2 * par.x
                       + wy0 * pbt.x + wy1 * pbc.x + wy2 * pbb.x;
            float div2 = wx0 * pal.y + wx1 * pac.y + wx2 * par.y
                       + wy0 * pbt.y + wy1 * pbc.y + wy2 * pbb.y;
            float nu1 = v1 + theta * div1;
            float nu2 = v2 + theta * div2;
            if (!((inbm >> s) & 1u)) { nu1 = 0.f; nu2 = 0.f; }  // zero-pad
            float2 nuv = make_float2(nu1, nu2);
            ruv[s] = nuv; su[idx] = nuv;
        }
        __syncthreads();
        if (phase == 2 && k == 5) break;   // 20th p-update is dead code

        // p-phase over li,lj in [k, REG-1-2k]  (valid cone of p^k)
        const int hi_p = REG - 1 - 2 * k;
        #pragma unroll
        for (int s = 0; s < SLOTS; ++s) {
            int idx = tid + s * TPB;
            if (idx >= NPX) continue;
            int li = lis[s], lj = ljs[s];
            if (li < lo || li > hi_p || lj < lo || lj > hi_p) continue;
            float2 uc = ruv[s];
            float2 uR = su[idx + 1];
            float2 uB = su[idx + REG];
            float gu1x = uR.x - uc.x, gu1y = uB.x - uc.x;
            float gu2x = uR.y - uc.y, gu2y = uB.y - uc.y;
            float2 pac = spa[idx], pbc = spb[idx];
            float d1 = 1.f + r * (fabsf(gu1x) + fabsf(gu1y));
            float id1 = __builtin_amdgcn_rcpf(d1);
            float np11 = (pac.x + r * gu1x) * id1;
            float np12 = (pbc.x + r * gu1y) * id1;
            float d2 = 1.f + r * (fabsf(gu2x) + fabsf(gu2y));
            float id2 = __builtin_amdgcn_rcpf(d2);
            float np21 = (pac.y + r * gu2x) * id2;
            float np22 = (pbc.y + r * gu2y) * id2;
            if (!((inbm >> s) & 1u)) { np11 = 0.f; np12 = 0.f; np21 = 0.f; np22 = 0.f; }
            spa[idx] = make_float2(np11, np21);
            spb[idx] = make_float2(np12, np22);
        }
        __syncthreads();
    }

    // ---- epilogue ---------------------------------------------------------
    if (phase != 2) {
        // write back interior [0,63]^2 (li,lj in [6,69])
        #pragma unroll
        for (int s = 0; s < SLOTS; ++s) {
            int idx = tid + s * TPB;
            if (idx >= NPX) continue;
            int li = lis[s], lj = ljs[s];
            if (li < HALO_L || li >= HALO_L + T || lj < HALO_L || lj >= HALO_L + T) continue;
            int gl = (li << 9) + lj + cb;
            ug[gbase + gl] = ruv[s];
            float2 pa = spa[idx], pb = spb[idx];
            pg[gbase + gl] = make_float4(pa.x, pa.y, pb.x, pb.y);
        }
    } else {
        // fused avgpool(3,1,1, /9 always); u^5 valid on [-1,64] — exact fit
        const float inv9 = 1.f / 9.f;
        #pragma unroll
        for (int s = 0; s < SLOTS; ++s) {
            int idx = tid + s * TPB;
            if (idx >= NPX) continue;
            int li = lis[s], lj = ljs[s];
            if (li < HALO_L || li >= HALO_L + T || lj < HALO_L || lj >= HALO_L + T) continue;
            float2 a0 = su[idx - REG - 1], a1 = su[idx - REG], a2 = su[idx - REG + 1];
            float2 b0 = su[idx - 1],       b1 = su[idx],       b2 = su[idx + 1];
            float2 c0 = su[idx + REG - 1], c1 = su[idx + REG], c2 = su[idx + REG + 1];
            float s1 = a0.x + a1.x + a2.x + b0.x + b1.x + b2.x + c0.x + c1.x + c2.x;
            float s2 = a0.y + a1.y + a2.y + b0.y + b1.y + b2.y + c0.y + c1.y + c2.y;
            int gl = (li << 9) + lj + cb;
            out[(size_t)bimg * 2 * HW + gl]      = s1 * inv9;
            out[(size_t)bimg * 2 * HW + HW + gl] = s2 * inv9;
        }
    }
}

// --------------------------------------------------------------- launch ---
extern "C" void kernel_launch(void* const* d_in, const int* in_sizes, int n_in,
                              void* d_out, int out_size, void* d_ws, size_t ws_size,
                              hipStream_t stream) {
    const float* x     = (const float*)d_in[0];
    const float* lam   = (const float*)d_in[1];
    const float* tau   = (const float*)d_in[2];
    const float* theta = (const float*)d_in[3];
    const float* wx    = (const float*)d_in[4];
    const float* wy    = (const float*)d_in[5];
    float* out = (float*)d_out;

    float*  ws = (float*)d_ws;
    float2* ug = (float2*)ws;                         // 8 MB
    float4* pg = (float4*)(ws + (size_t)2 * NTOT);    // 16 MB

    for (int c = 0; c < 4; ++c) {
        int phase = (c == 0) ? 0 : (c == 3) ? 2 : 1;
        k_fused<<<dim3(NBLK), dim3(TPB), 0, stream>>>(
            x, ug, pg, lam, tau, theta, wx, wy, out, phase);
    }
}

// Round 3
// 428.308 us; speedup vs baseline: 1.0033x; 1.0033x over previous
//
#include <hip/hip_runtime.h>

// TV-L1 optical flow, B=4, 512x512, 20 iters — temporal blocking (ghost zones)
// R8: fix R7's no-op. __launch_bounds__(TPB,1) itself lowers to
// amdgpu-waves-per-eu min=1, which shadowed our amdgpu_waves_per_eu(4,4)
// (duplicate attribute dropped) -> allocator kept targeting 8 waves/EU
// (64 VGPRs) and spilled ~70 dwords/thread to scratch (185 MB excess FETCH,
// 74 MB excess WRITE per dispatch in R6/R7 counters). Here we drop
// __launch_bounds__ and use amdgpu_flat_work_group_size(1024,1024) +
// amdgpu_waves_per_eu(4,4): occupancy pinned to the LDS-imposed 4 waves/EU
// -> VGPR budget 128, no spill incentive.
// Carried from R6:
//   - gl recomputed as (li<<9)+lj+cb (no gofs array).
//   - p-state center values read from LDS in main loop (no rpa/rpb mirrors).
//   - soft-threshold select as d = clamp(rho*rnv, -tl, tl) (v_med3), exact
//     vs reference (|rho|<th <=> |rho*rnv|<tl, continuous at boundary).
//   - inb[] packed into a single bitmask VGPR.
//   LDS: su=(u1,u2), spa=(p11,p21), spb=(p12,p22), 3 x 6400 x 8B = 153.6 KB.
// Halo L=6/R=10 (80x80 region per 64x64 tile). Zero-padding reproduced by
// forcing u=p=0 on out-of-image pixels. Last kernel skips the dead 20th
// p-update and fuses the 3x3 avgpool.

#define HH 512
#define WW 512
#define BB 4
constexpr int HW   = HH * WW;
constexpr int NTOT = BB * HW;
constexpr float EPS = 1e-8f;

#define T 64          // output tile edge
#define HALO_L 6      // left/top halo
#define REG 80        // region edge = 64 + 6 + 10
#define NPX (REG * REG)   // 6400
#define TPB 1024
#define SLOTS 7       // ceil(6400/1024)
#define NBLK 256      // 4 images x 8x8 tiles
#define XR 82         // x1 staging edge (region + 1-ring for 3x3 gradient)
#define XN (XR * XR)  // 6724 <= 12800 floats available in spa

// phase: 0 = first (u,p zero-init, write back), 1 = middle (load, write
// back), 2 = last (load, 5 u-phases + 4 p-phases, fused avgpool -> out).
__global__
__attribute__((amdgpu_flat_work_group_size(TPB, TPB), amdgpu_waves_per_eu(4, 4)))
void k_fused(
    const float* __restrict__ x,
    float2* __restrict__ ug, float4* __restrict__ pg,
    const float* __restrict__ lam_p, const float* __restrict__ tau_p,
    const float* __restrict__ theta_p,
    const float* __restrict__ wxp, const float* __restrict__ wyp,
    float* __restrict__ out, int phase)
{
    __shared__ float2 su[NPX];    // (u1,u2)
    __shared__ float2 spa[NPX];   // (p11,p21); doubles as x1 staging buffer
    __shared__ float2 spb[NPX];   // (p12,p22)   -> 153.6 KB total

    const int tid  = threadIdx.x;
    const int blk  = blockIdx.x;
    const int bimg = blk >> 6;
    const int t    = blk & 63;
    const int gi0  = (t >> 3) * T;
    const int gj0  = (t & 7) * T;

    const float lam = lam_p[0], theta = theta_p[0];
    const float r   = tau_p[0] / theta;
    const float tl  = theta * lam;
    const float wx0 = wxp[0], wx1 = wxp[1], wx2 = wxp[2];
    const float wy0 = wyp[0], wy1 = wyp[1], wy2 = wyp[2];

    const int gbase = bimg * HW;
    const int cb    = (gi0 - HALO_L) * WW + (gj0 - HALO_L);  // gl=(li<<9)+lj+cb
    const float* x0p = x + (size_t)bimg * 2 * HW;
    const float* x1p = x0p + HW;

    int  lis[SLOTS], ljs[SLOTS];
    unsigned inbm = 0u;           // bit s: slot s own-pixel is in-image
    float2 ruv[SLOTS];            // own-pixel u mirror (hot in both phases)
    float2 tpa[SLOTS], tpb[SLOTS];  // pass1->pass3 p-state temps ONLY
    float  x0v[SLOTS];            // pass1->pass2 temp ONLY

    // ---- pass 1: stage x1 into spa-as-float; precompute per-slot indices;
    //      issue state loads early (consumed in pass 3, overlap statics) ----
    #pragma unroll
    for (int s = 0; s < SLOTS; ++s) {
        int idx = tid + s * TPB;
        if (idx < XN) {
            int li = idx / XR, lj = idx - li * XR;
            int gi = gi0 + li - (HALO_L + 1), gj = gj0 + lj - (HALO_L + 1);
            bool in = ((unsigned)gi < HH) & ((unsigned)gj < WW);
            ((float*)spa)[idx] = in ? x1p[gi * WW + gj] : 0.f;
        }
        if (idx < NPX) {
            int li = idx / REG, lj = idx - li * REG;
            lis[s] = li; ljs[s] = lj;
            int gi = gi0 + li - HALO_L, gj = gj0 + lj - HALO_L;
            bool in = ((unsigned)gi < HH) & ((unsigned)gj < WW);
            inbm |= (in ? (1u << s) : 0u);
            int gl = (li << 9) + lj + cb;     // == gi*WW+gj, valid only when in
            float2 uv = make_float2(0.f, 0.f);
            float4 p4 = make_float4(0.f, 0.f, 0.f, 0.f);
            float xv = 0.f;
            if (in) {
                xv = x0p[gl];
                if (phase != 0) {
                    uv = ug[gbase + gl];
                    p4 = pg[gbase + gl];
                }
            }
            x0v[s] = xv;
            ruv[s] = uv;
            tpa[s] = make_float2(p4.x, p4.y);
            tpb[s] = make_float2(p4.z, p4.w);
        }
    }
    __syncthreads();

    // ---- pass 2: statics (gx,gy,rc,1/nm) from staged x1 -------------------
    float rgx[SLOTS], rgy[SLOTS], rrc[SLOTS], rnv[SLOTS];
    const float* stg = (const float*)spa;
    #pragma unroll
    for (int s = 0; s < SLOTS; ++s) {
        int idx = tid + s * TPB;
        if (idx < NPX) {
            int sc = (lis[s] + 1) * XR + (ljs[s] + 1);
            float a00 = stg[sc - XR - 1], a01 = stg[sc - XR], a02 = stg[sc - XR + 1];
            float a10 = stg[sc - 1],      a11 = stg[sc],      a12 = stg[sc + 1];
            float a20 = stg[sc + XR - 1], a21 = stg[sc + XR], a22 = stg[sc + XR + 1];
            const float c6 = 1.f / 6.f;
            float gxv = c6 * (-a00 + a02 - 2.f * a10 + 2.f * a12 - a20 + a22);
            float gyv = c6 * (-a00 - 2.f * a01 - a02 + a20 + 2.f * a21 + a22);
            float nm  = gxv * gxv + gyv * gyv + EPS;
            rgx[s] = gxv; rgy[s] = gyv;
            rrc[s] = a11 - x0v[s];           // zero-padded conv semantics held
            rnv[s] = __builtin_amdgcn_rcpf(nm);
        }
    }
    __syncthreads();

    // ---- pass 3: fill LDS state (overwrites staging) ----------------------
    #pragma unroll
    for (int s = 0; s < SLOTS; ++s) {
        int idx = tid + s * TPB;
        if (idx < NPX) {
            su[idx]  = ruv[s];
            spa[idx] = tpa[s];
            spb[idx] = tpb[s];
        }
    }
    __syncthreads();

    // ---- 5 fused iterations ----------------------------------------------
    for (int k = 1; k <= 5; ++k) {
        // u-phase over li,lj in [k, REG-2k]  (valid cone of u^k)
        const int lo = k, hi_u = REG - 2 * k;
        #pragma unroll
        for (int s = 0; s < SLOTS; ++s) {
            int idx = tid + s * TPB;
            if (idx >= NPX) continue;
            int li = lis[s], lj = ljs[s];
            if (li < lo || li > hi_u || lj < lo || lj > hi_u) continue;
            float2 uv = ruv[s];
            float rho = rrc[s] + rgx[s] * uv.x + rgy[s] * uv.y;
            // |rho| < th  <=>  |rho*rnv| < tl  (nm>0); boundary continuous,
            // so d = clamp(rho*rnv, -tl, tl) == reference select (v_med3).
            float tt = rho * rnv[s];
            float d  = fminf(fmaxf(tt, -tl), tl);
            float v1 = uv.x - d * rgx[s];
            float v2 = uv.y - d * rgy[s];
            float2 pal = spa[idx - 1],   pac = spa[idx],   par = spa[idx + 1];
            float2 pbt = spb[idx - REG], pbc = spb[idx],   pbb = spb[idx + REG];
            float div1 = wx0 * pal.x + wx1 * pac.x + wx2 * par.x
                       + wy0 * pbt.x + wy1 * pbc.x + wy2 * pbb.x;
            float div2 = wx0 * pal.y + wx1 * pac.y + wx2 * par.y
                       + wy0 * pbt.y + wy1 * pbc.y + wy2 * pbb.y;
            float nu1 = v1 + theta * div1;
            float nu2 = v2 + theta * div2;
            if (!((inbm >> s) & 1u)) { nu1 = 0.f; nu2 = 0.f; }  // zero-pad
            float2 nuv = make_float2(nu1, nu2);
            ruv[s] = nuv; su[idx] = nuv;
        }
        __syncthreads();
        if (phase == 2 && k == 5) break;   // 20th p-update is dead code

        // p-phase over li,lj in [k, REG-1-2k]  (valid cone of p^k)
        const int hi_p = REG - 1 - 2 * k;
        #pragma unroll
        for (int s = 0; s < SLOTS; ++s) {
            int idx = tid + s * TPB;
            if (idx >= NPX) continue;
            int li = lis[s], lj = ljs[s];
            if (li < lo || li > hi_p || lj < lo || lj > hi_p) continue;
            float2 uc = ruv[s];
            float2 uR = su[idx + 1];
            float2 uB = su[idx + REG];
            float gu1x = uR.x - uc.x, gu1y = uB.x - uc.x;
            float gu2x = uR.y - uc.y, gu2y = uB.y - uc.y;
            float2 pac = spa[idx], pbc = spb[idx];
            float d1 = 1.f + r * (fabsf(gu1x) + fabsf(gu1y));
            float id1 = __builtin_amdgcn_rcpf(d1);
            float np11 = (pac.x + r * gu1x) * id1;
            float np12 = (pbc.x + r * gu1y) * id1;
            float d2 = 1.f + r * (fabsf(gu2x) + fabsf(gu2y));
            float id2 = __builtin_amdgcn_rcpf(d2);
            float np21 = (pac.y + r * gu2x) * id2;
            float np22 = (pbc.y + r * gu2y) * id2;
            if (!((inbm >> s) & 1u)) { np11 = 0.f; np12 = 0.f; np21 = 0.f; np22 = 0.f; }
            spa[idx] = make_float2(np11, np21);
            spb[idx] = make_float2(np12, np22);
        }
        __syncthreads();
    }

    // ---- epilogue ---------------------------------------------------------
    if (phase != 2) {
        // write back interior [0,63]^2 (li,lj in [6,69])
        #pragma unroll
        for (int s = 0; s < SLOTS; ++s) {
            int idx = tid + s * TPB;
            if (idx >= NPX) continue;
            int li = lis[s], lj = ljs[s];
            if (li < HALO_L || li >= HALO_L + T || lj < HALO_L || lj >= HALO_L + T) continue;
            int gl = (li << 9) + lj + cb;
            ug[gbase + gl] = ruv[s];
            float2 pa = spa[idx], pb = spb[idx];
            pg[gbase + gl] = make_float4(pa.x, pa.y, pb.x, pb.y);
        }
    } else {
        // fused avgpool(3,1,1, /9 always); u^5 valid on [-1,64] — exact fit
        const float inv9 = 1.f / 9.f;
        #pragma unroll
        for (int s = 0; s < SLOTS; ++s) {
            int idx = tid + s * TPB;
            if (idx >= NPX) continue;
            int li = lis[s], lj = ljs[s];
            if (li < HALO_L || li >= HALO_L + T || lj < HALO_L || lj >= HALO_L + T) continue;
            float2 a0 = su[idx - REG - 1], a1 = su[idx - REG], a2 = su[idx - REG + 1];
            float2 b0 = su[idx - 1],       b1 = su[idx],       b2 = su[idx + 1];
            float2 c0 = su[idx + REG - 1], c1 = su[idx + REG], c2 = su[idx + REG + 1];
            float s1 = a0.x + a1.x + a2.x + b0.x + b1.x + b2.x + c0.x + c1.x + c2.x;
            float s2 = a0.y + a1.y + a2.y + b0.y + b1.y + b2.y + c0.y + c1.y + c2.y;
            int gl = (li << 9) + lj + cb;
            out[(size_t)bimg * 2 * HW + gl]      = s1 * inv9;
            out[(size_t)bimg * 2 * HW + HW + gl] = s2 * inv9;
        }
    }
}

// --------------------------------------------------------------- launch ---
extern "C" void kernel_launch(void* const* d_in, const int* in_sizes, int n_in,
                              void* d_out, int out_size, void* d_ws, size_t ws_size,
                              hipStream_t stream) {
    const float* x     = (const float*)d_in[0];
    const float* lam   = (const float*)d_in[1];
    const float* tau   = (const float*)d_in[2];
    const float* theta = (const float*)d_in[3];
    const float* wx    = (const float*)d_in[4];
    const float* wy    = (const float*)d_in[5];
    float* out = (float*)d_out;

    float*  ws = (float*)d_ws;
    float2* ug = (float2*)ws;                         // 8 MB
    float4* pg = (float4*)(ws + (size_t)2 * NTOT);    // 16 MB

    for (int c = 0; c < 4; ++c) {
        int phase = (c == 0) ? 0 : (c == 3) ? 2 : 1;
        k_fused<<<dim3(NBLK), dim3(TPB), 0, stream>>>(
            x, ug, pg, lam, tau, theta, wx, wy, out, phase);
    }
}

// Round 4
// 192.832 us; speedup vs baseline: 2.2285x; 2.2211x over previous
//
#include <hip/hip_runtime.h>

// TV-L1 optical flow, B=4, 512x512, 20 iters — temporal blocking (ghost zones)
// R9: revert to the R5 kernel-body structure BYTE-FOR-BYTE (gofs/inb arrays,
// rpa/rpb register mirrors, rth, ternary soft-threshold select) — the R6-R8
// "register diet" variants tripped an IR-level array demotion to scratch
// (VGPR_Count=64 with ~185 MB excess FETCH; occupancy attributes were no-ops
// because the demotion happens before regalloc). R5's structure empirically
// compiles clean.
// The round's single change is LAUNCH GEOMETRY: T=64 -> T=32.
//   REG=48, LDS = 3 x 2304 x 8B = 55.3 KB -> 2 resident blocks/CU
//   (R5 had 153.6 KB -> 1 block/CU, so prologue loads / barrier phases /
//   epilogue stores serialized per CU). With 2 blocks/CU + a 1024-block
//   grid, one block's global phases overlap the other's LDS/VALU phases.
// Cost: redundant compute 48^2/32^2 = 2.25x (was 1.56x), halo reads +45%.
//   LDS: su=(u1,u2), spa=(p11,p21), spb=(p12,p22), 3 x 2304 x 8B = 55.3 KB.
// Halo L=6/R=10 (48x48 region per 32x32 tile). Zero-padding reproduced by
// forcing u=p=0 on out-of-image pixels. Last kernel skips the dead 20th
// p-update and fuses the 3x3 avgpool.

#define HH 512
#define WW 512
#define BB 4
constexpr int HW   = HH * WW;
constexpr int NTOT = BB * HW;
constexpr float EPS = 1e-8f;

#define T 32          // output tile edge
#define HALO_L 6      // left/top halo
#define REG 48        // region edge = 32 + 6 + 10
#define NPX (REG * REG)   // 2304
#define TPB 512
#define SLOTS 5       // ceil(2304/512)
#define NBLK 1024     // 4 images x 16x16 tiles
#define XR 50         // x1 staging edge (region + 1-ring for 3x3 gradient)
#define XN (XR * XR)  // 2500 <= 4608 floats available in spa

// phase: 0 = first (u,p zero-init, write back), 1 = middle (load, write
// back), 2 = last (load, 5 u-phases + 4 p-phases, fused avgpool -> out).
__global__ __launch_bounds__(TPB, 1) void k_fused(
    const float* __restrict__ x,
    float2* __restrict__ ug, float4* __restrict__ pg,
    const float* __restrict__ lam_p, const float* __restrict__ tau_p,
    const float* __restrict__ theta_p,
    const float* __restrict__ wxp, const float* __restrict__ wyp,
    float* __restrict__ out, int phase)
{
    __shared__ float2 su[NPX];    // (u1,u2)
    __shared__ float2 spa[NPX];   // (p11,p21); doubles as x1 staging buffer
    __shared__ float2 spb[NPX];   // (p12,p22)   -> 55.3 KB total

    const int tid  = threadIdx.x;
    const int blk  = blockIdx.x;
    const int bimg = blk >> 8;
    const int t    = blk & 255;
    const int gi0  = (t >> 4) * T;
    const int gj0  = (t & 15) * T;

    const float lam = lam_p[0], theta = theta_p[0];
    const float r   = tau_p[0] / theta;
    const float tl  = theta * lam;
    const float wx0 = wxp[0], wx1 = wxp[1], wx2 = wxp[2];
    const float wy0 = wyp[0], wy1 = wyp[1], wy2 = wyp[2];

    const int gbase = bimg * HW;
    const float* x0p = x + (size_t)bimg * 2 * HW;
    const float* x1p = x0p + HW;

    int  lis[SLOTS], ljs[SLOTS], gofs[SLOTS];
    bool inb[SLOTS];
    float2 ruv[SLOTS], rpa[SLOTS], rpb[SLOTS];  // own-pixel mirrors
    float  x0v[SLOTS];

    // ---- pass 1: stage x1 into spa-as-float; precompute per-slot indices;
    //      issue state loads early (consumed in pass 3, overlap statics) ----
    #pragma unroll
    for (int s = 0; s < SLOTS; ++s) {
        int idx = tid + s * TPB;
        if (idx < XN) {
            int li = idx / XR, lj = idx - li * XR;
            int gi = gi0 + li - (HALO_L + 1), gj = gj0 + lj - (HALO_L + 1);
            bool in = ((unsigned)gi < HH) & ((unsigned)gj < WW);
            ((float*)spa)[idx] = in ? x1p[gi * WW + gj] : 0.f;
        }
        if (idx < NPX) {
            int li = idx / REG, lj = idx - li * REG;
            lis[s] = li; ljs[s] = lj;
            int gi = gi0 + li - HALO_L, gj = gj0 + lj - HALO_L;
            bool in = ((unsigned)gi < HH) & ((unsigned)gj < WW);
            inb[s] = in;
            int gl = gi * WW + gj;            // valid only when in
            gofs[s] = gl;
            float2 uv = make_float2(0.f, 0.f);
            float4 p4 = make_float4(0.f, 0.f, 0.f, 0.f);
            float xv = 0.f;
            if (in) {
                xv = x0p[gl];
                if (phase != 0) {
                    uv = ug[gbase + gl];
                    p4 = pg[gbase + gl];
                }
            }
            x0v[s] = xv;
            ruv[s] = uv;
            rpa[s] = make_float2(p4.x, p4.y);
            rpb[s] = make_float2(p4.z, p4.w);
        }
    }
    __syncthreads();

    // ---- pass 2: statics (gx,gy,rc,th,1/nm) from staged x1 ---------------
    float rgx[SLOTS], rgy[SLOTS], rrc[SLOTS], rth[SLOTS], rnv[SLOTS];
    const float* stg = (const float*)spa;
    #pragma unroll
    for (int s = 0; s < SLOTS; ++s) {
        int idx = tid + s * TPB;
        if (idx < NPX) {
            int sc = (lis[s] + 1) * XR + (ljs[s] + 1);
            float a00 = stg[sc - XR - 1], a01 = stg[sc - XR], a02 = stg[sc - XR + 1];
            float a10 = stg[sc - 1],      a11 = stg[sc],      a12 = stg[sc + 1];
            float a20 = stg[sc + XR - 1], a21 = stg[sc + XR], a22 = stg[sc + XR + 1];
            const float c6 = 1.f / 6.f;
            float gxv = c6 * (-a00 + a02 - 2.f * a10 + 2.f * a12 - a20 + a22);
            float gyv = c6 * (-a00 - 2.f * a01 - a02 + a20 + 2.f * a21 + a22);
            float nm  = gxv * gxv + gyv * gyv + EPS;
            rgx[s] = gxv; rgy[s] = gyv;
            rrc[s] = a11 - x0v[s];           // zero-padded conv semantics held
            rth[s] = tl * nm;
            rnv[s] = __builtin_amdgcn_rcpf(nm);
        }
    }
    __syncthreads();

    // ---- pass 3: fill LDS state (overwrites staging) ---------------------
    #pragma unroll
    for (int s = 0; s < SLOTS; ++s) {
        int idx = tid + s * TPB;
        if (idx < NPX) {
            su[idx]  = ruv[s];
            spa[idx] = rpa[s];
            spb[idx] = rpb[s];
        }
    }
    __syncthreads();

    // ---- 5 fused iterations ---------------------------------------------
    for (int k = 1; k <= 5; ++k) {
        // u-phase over li,lj in [k, REG-2k]  (valid cone of u^k)
        const int lo = k, hi_u = REG - 2 * k;
        #pragma unroll
        for (int s = 0; s < SLOTS; ++s) {
            int idx = tid + s * TPB;
            if (idx >= NPX) continue;
            int li = lis[s], lj = ljs[s];
            if (li < lo || li > hi_u || lj < lo || lj > hi_u) continue;
            float2 uv = ruv[s];
            float rho = rrc[s] + rgx[s] * uv.x + rgy[s] * uv.y;
            // th>0 always (nm>=EPS, tl>0), so rho==0 takes the inside branch:
            // copysignf(tl,0) is never selected -> sign(0)=0 handled.
            float d = (fabsf(rho) < rth[s]) ? rho * rnv[s] : copysignf(tl, rho);
            float v1 = uv.x - d * rgx[s];
            float v2 = uv.y - d * rgy[s];
            float2 pal = spa[idx - 1],   par = spa[idx + 1];
            float2 pbt = spb[idx - REG], pbb = spb[idx + REG];
            float2 pac = rpa[s],         pbc = rpb[s];
            float div1 = wx0 * pal.x + wx1 * pac.x + wx2 * par.x
                       + wy0 * pbt.x + wy1 * pbc.x + wy2 * pbb.x;
            float div2 = wx0 * pal.y + wx1 * pac.y + wx2 * par.y
                       + wy0 * pbt.y + wy1 * pbc.y + wy2 * pbb.y;
            float nu1 = v1 + theta * div1;
            float nu2 = v2 + theta * div2;
            if (!inb[s]) { nu1 = 0.f; nu2 = 0.f; }   // zero-padding semantics
            float2 nuv = make_float2(nu1, nu2);
            ruv[s] = nuv; su[idx] = nuv;
        }
        __syncthreads();
        if (phase == 2 && k == 5) break;   // 20th p-update is dead code

        // p-phase over li,lj in [k, REG-1-2k]  (valid cone of p^k)
        const int hi_p = REG - 1 - 2 * k;
        #pragma unroll
        for (int s = 0; s < SLOTS; ++s) {
            int idx = tid + s * TPB;
            if (idx >= NPX) continue;
            int li = lis[s], lj = ljs[s];
            if (li < lo || li > hi_p || lj < lo || lj > hi_p) continue;
            float2 uc = ruv[s];
            float2 uR = su[idx + 1];
            float2 uB = su[idx + REG];
            float gu1x = uR.x - uc.x, gu1y = uB.x - uc.x;
            float gu2x = uR.y - uc.y, gu2y = uB.y - uc.y;
            float d1 = 1.f + r * (fabsf(gu1x) + fabsf(gu1y));
            float id1 = __builtin_amdgcn_rcpf(d1);
            float np11 = (rpa[s].x + r * gu1x) * id1;
            float np12 = (rpb[s].x + r * gu1y) * id1;
            float d2 = 1.f + r * (fabsf(gu2x) + fabsf(gu2y));
            float id2 = __builtin_amdgcn_rcpf(d2);
            float np21 = (rpa[s].y + r * gu2x) * id2;
            float np22 = (rpb[s].y + r * gu2y) * id2;
            if (!inb[s]) { np11 = 0.f; np12 = 0.f; np21 = 0.f; np22 = 0.f; }
            float2 npa = make_float2(np11, np21);
            float2 npb = make_float2(np12, np22);
            rpa[s] = npa; rpb[s] = npb;
            spa[idx] = npa; spb[idx] = npb;
        }
        __syncthreads();
    }

    // ---- epilogue --------------------------------------------------------
    if (phase != 2) {
        // write back interior [0,31]^2 (li,lj in [6,37]) from mirrors
        #pragma unroll
        for (int s = 0; s < SLOTS; ++s) {
            int idx = tid + s * TPB;
            if (idx >= NPX) continue;
            int li = lis[s], lj = ljs[s];
            if (li < HALO_L || li >= HALO_L + T || lj < HALO_L || lj >= HALO_L + T) continue;
            int gl = gofs[s];
            ug[gbase + gl] = ruv[s];
            pg[gbase + gl] = make_float4(rpa[s].x, rpa[s].y, rpb[s].x, rpb[s].y);
        }
    } else {
        // fused avgpool(3,1,1, /9 always); u^5 valid on [-1,32] — exact fit
        const float inv9 = 1.f / 9.f;
        #pragma unroll
        for (int s = 0; s < SLOTS; ++s) {
            int idx = tid + s * TPB;
            if (idx >= NPX) continue;
            int li = lis[s], lj = ljs[s];
            if (li < HALO_L || li >= HALO_L + T || lj < HALO_L || lj >= HALO_L + T) continue;
            float2 a0 = su[idx - REG - 1], a1 = su[idx - REG], a2 = su[idx - REG + 1];
            float2 b0 = su[idx - 1],       b1 = su[idx],       b2 = su[idx + 1];
            float2 c0 = su[idx + REG - 1], c1 = su[idx + REG], c2 = su[idx + REG + 1];
            float s1 = a0.x + a1.x + a2.x + b0.x + b1.x + b2.x + c0.x + c1.x + c2.x;
            float s2 = a0.y + a1.y + a2.y + b0.y + b1.y + b2.y + c0.y + c1.y + c2.y;
            int gl = gofs[s];
            out[(size_t)bimg * 2 * HW + gl]      = s1 * inv9;
            out[(size_t)bimg * 2 * HW + HW + gl] = s2 * inv9;
        }
    }
}

// --------------------------------------------------------------- launch ---
extern "C" void kernel_launch(void* const* d_in, const int* in_sizes, int n_in,
                              void* d_out, int out_size, void* d_ws, size_t ws_size,
                              hipStream_t stream) {
    const float* x     = (const float*)d_in[0];
    const float* lam   = (const float*)d_in[1];
    const float* tau   = (const float*)d_in[2];
    const float* theta = (const float*)d_in[3];
    const float* wx    = (const float*)d_in[4];
    const float* wy    = (const float*)d_in[5];
    float* out = (float*)d_out;

    float*  ws = (float*)d_ws;
    float2* ug = (float2*)ws;                         // 8 MB
    float4* pg = (float4*)(ws + (size_t)2 * NTOT);    // 16 MB

    for (int c = 0; c < 4; ++c) {
        int phase = (c == 0) ? 0 : (c == 3) ? 2 : 1;
        k_fused<<<dim3(NBLK), dim3(TPB), 0, stream>>>(
            x, ug, pg, lam, tau, theta, wx, wy, out, phase);
    }
}

// Round 5
// 177.436 us; speedup vs baseline: 2.4219x; 1.0868x over previous
//
#include <hip/hip_runtime.h>

// TV-L1 optical flow, B=4, 512x512, 20 iters — temporal blocking (ghost zones)
// R10: R9 geometry (T=32, REG=48, LDS 55.3 KB -> 2 blocks/CU) with TPB
// 512 -> 768. R9 normalization: 0.425M slot-phases/us vs R5's 0.334 — the
// 2-blocks/CU overlap works, but 4 waves/SIMD still latency-bound
// (VALUBusy 30%). 768 threads x 2 blocks = 1536/CU = 6 waves/SIMD (+50%
// hiding), and 768*3 == 2304 == NPX exactly: 3 slots, zero guard waste,
// all idx<NPX guards provably true and removed. VGPR ceiling at 6 waves/EU
// is 85; SLOTS=3 arrays ~48 regs + temps fits. Pass 1 split: 1a = state
// loads + indices (3 slots), 1b = x1 staging (4 iters, XN=2500) — both
// load streams in flight before the first barrier. Body otherwise
// byte-identical to the R5/R9 structure (R6-R8's edits tripped an IR-level
// array demotion to scratch; don't touch the body).
//   LDS: su=(u1,u2), spa=(p11,p21), spb=(p12,p22), 3 x 2304 x 8B = 55.3 KB.
// Halo L=6/R=10 (48x48 region per 32x32 tile). Zero-padding reproduced by
// forcing u=p=0 on out-of-image pixels. Last kernel skips the dead 20th
// p-update and fuses the 3x3 avgpool.

#define HH 512
#define WW 512
#define BB 4
constexpr int HW   = HH * WW;
constexpr int NTOT = BB * HW;
constexpr float EPS = 1e-8f;

#define T 32          // output tile edge
#define HALO_L 6      // left/top halo
#define REG 48        // region edge = 32 + 6 + 10
#define NPX (REG * REG)   // 2304
#define TPB 768
#define SLOTS 3       // 768*3 == 2304 exactly
#define NBLK 1024     // 4 images x 16x16 tiles
#define XR 50         // x1 staging edge (region + 1-ring for 3x3 gradient)
#define XN (XR * XR)  // 2500 <= 4608 floats available in spa
#define XSL 4         // ceil(2500/768) staging iterations

// phase: 0 = first (u,p zero-init, write back), 1 = middle (load, write
// back), 2 = last (load, 5 u-phases + 4 p-phases, fused avgpool -> out).
__global__ __launch_bounds__(TPB, 1) void k_fused(
    const float* __restrict__ x,
    float2* __restrict__ ug, float4* __restrict__ pg,
    const float* __restrict__ lam_p, const float* __restrict__ tau_p,
    const float* __restrict__ theta_p,
    const float* __restrict__ wxp, const float* __restrict__ wyp,
    float* __restrict__ out, int phase)
{
    __shared__ float2 su[NPX];    // (u1,u2)
    __shared__ float2 spa[NPX];   // (p11,p21); doubles as x1 staging buffer
    __shared__ float2 spb[NPX];   // (p12,p22)   -> 55.3 KB total

    const int tid  = threadIdx.x;
    const int blk  = blockIdx.x;
    const int bimg = blk >> 8;
    const int t    = blk & 255;
    const int gi0  = (t >> 4) * T;
    const int gj0  = (t & 15) * T;

    const float lam = lam_p[0], theta = theta_p[0];
    const float r   = tau_p[0] / theta;
    const float tl  = theta * lam;
    const float wx0 = wxp[0], wx1 = wxp[1], wx2 = wxp[2];
    const float wy0 = wyp[0], wy1 = wyp[1], wy2 = wyp[2];

    const int gbase = bimg * HW;
    const float* x0p = x + (size_t)bimg * 2 * HW;
    const float* x1p = x0p + HW;

    int  lis[SLOTS], ljs[SLOTS], gofs[SLOTS];
    bool inb[SLOTS];
    float2 ruv[SLOTS], rpa[SLOTS], rpb[SLOTS];  // own-pixel mirrors
    float  x0v[SLOTS];

    // ---- pass 1a: per-slot indices + state loads (issued first) ----------
    #pragma unroll
    for (int s = 0; s < SLOTS; ++s) {
        int idx = tid + s * TPB;                  // < NPX always (768*3=2304)
        int li = idx / REG, lj = idx - li * REG;
        lis[s] = li; ljs[s] = lj;
        int gi = gi0 + li - HALO_L, gj = gj0 + lj - HALO_L;
        bool in = ((unsigned)gi < HH) & ((unsigned)gj < WW);
        inb[s] = in;
        int gl = gi * WW + gj;            // valid only when in
        gofs[s] = gl;
        float2 uv = make_float2(0.f, 0.f);
        float4 p4 = make_float4(0.f, 0.f, 0.f, 0.f);
        float xv = 0.f;
        if (in) {
            xv = x0p[gl];
            if (phase != 0) {
                uv = ug[gbase + gl];
                p4 = pg[gbase + gl];
            }
        }
        x0v[s] = xv;
        ruv[s] = uv;
        rpa[s] = make_float2(p4.x, p4.y);
        rpb[s] = make_float2(p4.z, p4.w);
    }
    // ---- pass 1b: stage x1 into spa-as-float (overlaps 1a's loads) -------
    #pragma unroll
    for (int s = 0; s < XSL; ++s) {
        int idx = tid + s * TPB;
        if (idx < XN) {
            int li = idx / XR, lj = idx - li * XR;
            int gi = gi0 + li - (HALO_L + 1), gj = gj0 + lj - (HALO_L + 1);
            bool in = ((unsigned)gi < HH) & ((unsigned)gj < WW);
            ((float*)spa)[idx] = in ? x1p[gi * WW + gj] : 0.f;
        }
    }
    __syncthreads();

    // ---- pass 2: statics (gx,gy,rc,th,1/nm) from staged x1 ---------------
    float rgx[SLOTS], rgy[SLOTS], rrc[SLOTS], rth[SLOTS], rnv[SLOTS];
    const float* stg = (const float*)spa;
    #pragma unroll
    for (int s = 0; s < SLOTS; ++s) {
        int sc = (lis[s] + 1) * XR + (ljs[s] + 1);
        float a00 = stg[sc - XR - 1], a01 = stg[sc - XR], a02 = stg[sc - XR + 1];
        float a10 = stg[sc - 1],      a11 = stg[sc],      a12 = stg[sc + 1];
        float a20 = stg[sc + XR - 1], a21 = stg[sc + XR], a22 = stg[sc + XR + 1];
        const float c6 = 1.f / 6.f;
        float gxv = c6 * (-a00 + a02 - 2.f * a10 + 2.f * a12 - a20 + a22);
        float gyv = c6 * (-a00 - 2.f * a01 - a02 + a20 + 2.f * a21 + a22);
        float nm  = gxv * gxv + gyv * gyv + EPS;
        rgx[s] = gxv; rgy[s] = gyv;
        rrc[s] = a11 - x0v[s];           // zero-padded conv semantics held
        rth[s] = tl * nm;
        rnv[s] = __builtin_amdgcn_rcpf(nm);
    }
    __syncthreads();

    // ---- pass 3: fill LDS state (overwrites staging) ---------------------
    #pragma unroll
    for (int s = 0; s < SLOTS; ++s) {
        int idx = tid + s * TPB;
        su[idx]  = ruv[s];
        spa[idx] = rpa[s];
        spb[idx] = rpb[s];
    }
    __syncthreads();

    // ---- 5 fused iterations ---------------------------------------------
    for (int k = 1; k <= 5; ++k) {
        // u-phase over li,lj in [k, REG-2k]  (valid cone of u^k)
        const int lo = k, hi_u = REG - 2 * k;
        #pragma unroll
        for (int s = 0; s < SLOTS; ++s) {
            int idx = tid + s * TPB;
            int li = lis[s], lj = ljs[s];
            if (li < lo || li > hi_u || lj < lo || lj > hi_u) continue;
            float2 uv = ruv[s];
            float rho = rrc[s] + rgx[s] * uv.x + rgy[s] * uv.y;
            // th>0 always (nm>=EPS, tl>0), so rho==0 takes the inside branch:
            // copysignf(tl,0) is never selected -> sign(0)=0 handled.
            float d = (fabsf(rho) < rth[s]) ? rho * rnv[s] : copysignf(tl, rho);
            float v1 = uv.x - d * rgx[s];
            float v2 = uv.y - d * rgy[s];
            float2 pal = spa[idx - 1],   par = spa[idx + 1];
            float2 pbt = spb[idx - REG], pbb = spb[idx + REG];
            float2 pac = rpa[s],         pbc = rpb[s];
            float div1 = wx0 * pal.x + wx1 * pac.x + wx2 * par.x
                       + wy0 * pbt.x + wy1 * pbc.x + wy2 * pbb.x;
            float div2 = wx0 * pal.y + wx1 * pac.y + wx2 * par.y
                       + wy0 * pbt.y + wy1 * pbc.y + wy2 * pbb.y;
            float nu1 = v1 + theta * div1;
            float nu2 = v2 + theta * div2;
            if (!inb[s]) { nu1 = 0.f; nu2 = 0.f; }   // zero-padding semantics
            float2 nuv = make_float2(nu1, nu2);
            ruv[s] = nuv; su[idx] = nuv;
        }
        __syncthreads();
        if (phase == 2 && k == 5) break;   // 20th p-update is dead code

        // p-phase over li,lj in [k, REG-1-2k]  (valid cone of p^k)
        const int hi_p = REG - 1 - 2 * k;
        #pragma unroll
        for (int s = 0; s < SLOTS; ++s) {
            int idx = tid + s * TPB;
            int li = lis[s], lj = ljs[s];
            if (li < lo || li > hi_p || lj < lo || lj > hi_p) continue;
            float2 uc = ruv[s];
            float2 uR = su[idx + 1];
            float2 uB = su[idx + REG];
            float gu1x = uR.x - uc.x, gu1y = uB.x - uc.x;
            float gu2x = uR.y - uc.y, gu2y = uB.y - uc.y;
            float d1 = 1.f + r * (fabsf(gu1x) + fabsf(gu1y));
            float id1 = __builtin_amdgcn_rcpf(d1);
            float np11 = (rpa[s].x + r * gu1x) * id1;
            float np12 = (rpb[s].x + r * gu1y) * id1;
            float d2 = 1.f + r * (fabsf(gu2x) + fabsf(gu2y));
            float id2 = __builtin_amdgcn_rcpf(d2);
            float np21 = (rpa[s].y + r * gu2x) * id2;
            float np22 = (rpb[s].y + r * gu2y) * id2;
            if (!inb[s]) { np11 = 0.f; np12 = 0.f; np21 = 0.f; np22 = 0.f; }
            float2 npa = make_float2(np11, np21);
            float2 npb = make_float2(np12, np22);
            rpa[s] = npa; rpb[s] = npb;
            spa[idx] = npa; spb[idx] = npb;
        }
        __syncthreads();
    }

    // ---- epilogue --------------------------------------------------------
    if (phase != 2) {
        // write back interior [0,31]^2 (li,lj in [6,37]) from mirrors
        #pragma unroll
        for (int s = 0; s < SLOTS; ++s) {
            int li = lis[s], lj = ljs[s];
            if (li < HALO_L || li >= HALO_L + T || lj < HALO_L || lj >= HALO_L + T) continue;
            int gl = gofs[s];
            ug[gbase + gl] = ruv[s];
            pg[gbase + gl] = make_float4(rpa[s].x, rpa[s].y, rpb[s].x, rpb[s].y);
        }
    } else {
        // fused avgpool(3,1,1, /9 always); u^5 valid on [-1,32] — exact fit
        const float inv9 = 1.f / 9.f;
        #pragma unroll
        for (int s = 0; s < SLOTS; ++s) {
            int idx = tid + s * TPB;
            int li = lis[s], lj = ljs[s];
            if (li < HALO_L || li >= HALO_L + T || lj < HALO_L || lj >= HALO_L + T) continue;
            float2 a0 = su[idx - REG - 1], a1 = su[idx - REG], a2 = su[idx - REG + 1];
            float2 b0 = su[idx - 1],       b1 = su[idx],       b2 = su[idx + 1];
            float2 c0 = su[idx + REG - 1], c1 = su[idx + REG], c2 = su[idx + REG + 1];
            float s1 = a0.x + a1.x + a2.x + b0.x + b1.x + b2.x + c0.x + c1.x + c2.x;
            float s2 = a0.y + a1.y + a2.y + b0.y + b1.y + b2.y + c0.y + c1.y + c2.y;
            int gl = gofs[s];
            out[(size_t)bimg * 2 * HW + gl]      = s1 * inv9;
            out[(size_t)bimg * 2 * HW + HW + gl] = s2 * inv9;
        }
    }
}

// --------------------------------------------------------------- launch ---
extern "C" void kernel_launch(void* const* d_in, const int* in_sizes, int n_in,
                              void* d_out, int out_size, void* d_ws, size_t ws_size,
                              hipStream_t stream) {
    const float* x     = (const float*)d_in[0];
    const float* lam   = (const float*)d_in[1];
    const float* tau   = (const float*)d_in[2];
    const float* theta = (const float*)d_in[3];
    const float* wx    = (const float*)d_in[4];
    const float* wy    = (const float*)d_in[5];
    float* out = (float*)d_out;

    float*  ws = (float*)d_ws;
    float2* ug = (float2*)ws;                         // 8 MB
    float4* pg = (float4*)(ws + (size_t)2 * NTOT);    // 16 MB

    for (int c = 0; c < 4; ++c) {
        int phase = (c == 0) ? 0 : (c == 3) ? 2 : 1;
        k_fused<<<dim3(NBLK), dim3(TPB), 0, stream>>>(
            x, ug, pg, lam, tau, theta, wx, wy, out, phase);
    }
}